// Round 1
// 1139.284 us; speedup vs baseline: 1.3136x; 1.3136x over previous
//
#include <hip/hip_runtime.h>
#include <stdint.h>

#define B_  4
#define T_  1024
#define V_  32000
#define E_  1024
#define H_  16
#define HS_ 64

typedef unsigned short u16;
typedef __bf16 bf16x8 __attribute__((ext_vector_type(8)));
typedef float f32x4 __attribute__((ext_vector_type(4)));

// exact round-to-nearest-even fp32 -> bf16 (finite inputs)
static __device__ __forceinline__ u16 f2b(float x) {
  uint32_t u = __float_as_uint(x);
  uint32_t r = (u + 0x7FFFu + ((u >> 16) & 1u)) >> 16;
  return (u16)r;
}

static __device__ __forceinline__ void gl_lds16(const void* g, void* l) {
  __builtin_amdgcn_global_load_lds(
      (const __attribute__((address_space(1))) void*)g,
      (__attribute__((address_space(3))) void*)l, 16, 0, 0);
}

// ---------------------------------------------------------------- embed
// x[b,t,:] = tok_emb[tok[b,t],:] + pos_emb[t,:]  -> bf16
__global__ __launch_bounds__(256) void embed_kernel(
    const int* __restrict__ tok, const float* __restrict__ tokemb,
    const float* __restrict__ posemb, u16* __restrict__ xb) {
  int row = blockIdx.x;            // b*T + t
  int t = row & (T_ - 1);
  int v = tok[row];
  const float4* te = reinterpret_cast<const float4*>(tokemb + (size_t)v * E_);
  const float4* pe = reinterpret_cast<const float4*>(posemb + (size_t)t * E_);
  int u = threadIdx.x;             // E_/4 == 256 == blockDim
  float4 a = te[u], p = pe[u];
  ushort4 o;
  o.x = f2b(a.x + p.x); o.y = f2b(a.y + p.y);
  o.z = f2b(a.z + p.z); o.w = f2b(a.w + p.w);
  reinterpret_cast<ushort4*>(xb + (size_t)row * E_)[u] = o;
}

// ------------------------------------------------- transpose + cast to bf16
// src: fp32 R x C (row-major); dst: bf16 C x R (row-major); batch via blockIdx.z
__global__ __launch_bounds__(256) void transpose_cast_kernel(
    const float* __restrict__ src, u16* __restrict__ dst, int R, int C) {
  size_t bofs = (size_t)blockIdx.z * (size_t)R * (size_t)C;
  src += bofs; dst += bofs;
  __shared__ float tile[64][65];
  int tr = blockIdx.x * 64, tc = blockIdx.y * 64;
  int tid = threadIdx.x;
#pragma unroll
  for (int it = 0; it < 4; ++it) {
    int u = tid + it * 256;        // float4 index, 1024 total
    int i = u >> 4, j4 = (u & 15) << 2;
    float4 v = *reinterpret_cast<const float4*>(&src[(size_t)(tr + i) * C + tc + j4]);
    tile[i][j4] = v.x; tile[i][j4 + 1] = v.y; tile[i][j4 + 2] = v.z; tile[i][j4 + 3] = v.w;
  }
  __syncthreads();
#pragma unroll
  for (int it = 0; it < 4; ++it) {
    int u = tid + it * 256;
    int j = u >> 4, i4 = (u & 15) << 2;
    ushort4 o;
    o.x = f2b(tile[i4][j]);     o.y = f2b(tile[i4 + 1][j]);
    o.z = f2b(tile[i4 + 2][j]); o.w = f2b(tile[i4 + 3][j]);
    *reinterpret_cast<ushort4*>(&dst[(size_t)(tc + j) * R + tr + i4]) = o;
  }
}

// ---------------------------------------------------------------- GEMM
// C[M,N] = A[M,K](bf16) @ Bt[N,K](bf16)^T  (+bias, epilogue per MODE)
// MODE 0: scatter bf16 into kqv: K,Q as [b,h,t,d]; V TRANSPOSED as [b,h,d,t]
// MODE 1: bias + relu -> bf16 row-major [M,N]
// MODE 2: bias -> fp32 row-major [M,N]
template <int MODE>
__global__ __launch_bounds__(256) void gemm_bt_kernel(
    const u16* __restrict__ A, const u16* __restrict__ Bt,
    const float* __restrict__ bias, void* __restrict__ Cout,
    int M, int N, int K, int NT) {
  __shared__ __align__(16) u16 Al[128 * 32];
  __shared__ __align__(16) u16 Bl[128 * 32];
  int tid = threadIdx.x;
  int w = tid >> 6, lane = tid & 63;
  int tileM = blockIdx.x / NT, tileN = blockIdx.x % NT;
  int wm = w >> 1, wn = w & 1;

  f32x4 acc[4][4];
#pragma unroll
  for (int i = 0; i < 4; i++)
#pragma unroll
    for (int j = 0; j < 4; j++) acc[i][j] = (f32x4){0.f, 0.f, 0.f, 0.f};

  const u16* Abase = A + (size_t)(tileM * 128) * K;
  const u16* Bbase = Bt + (size_t)(tileN * 128) * K;
  // staging: chunk = w*2+c covers 16 rows; lane -> row chunk*16 + lane/4, k (lane&3)*8
  int srow = w * 32 + (lane >> 2);
  int skl  = (lane & 3) * 8;
  int mrow = wm * 64 + (lane & 15);
  int nrow = wn * 64 + (lane & 15);
  int kh = (lane >> 4) * 8;

  for (int k0 = 0; k0 < K; k0 += 32) {
    __syncthreads();  // previous iter done reading LDS
    const u16* ga = &Abase[(size_t)srow * K + k0 + skl];
    gl_lds16(ga, &Al[w * 1024]);
    gl_lds16(ga + (size_t)16 * K, &Al[w * 1024 + 512]);
    const u16* gb = &Bbase[(size_t)srow * K + k0 + skl];
    gl_lds16(gb, &Bl[w * 1024]);
    gl_lds16(gb + (size_t)16 * K, &Bl[w * 1024 + 512]);
    __syncthreads();  // staging visible (compiler drains vmcnt before barrier)

    bf16x8 af[4], bfr[4];
#pragma unroll
    for (int mi = 0; mi < 4; mi++)
      af[mi] = *reinterpret_cast<const bf16x8*>(&Al[(mrow + mi * 16) * 32 + kh]);
#pragma unroll
    for (int ni = 0; ni < 4; ni++)
      bfr[ni] = *reinterpret_cast<const bf16x8*>(&Bl[(nrow + ni * 16) * 32 + kh]);
#pragma unroll
    for (int mi = 0; mi < 4; mi++)
#pragma unroll
      for (int ni = 0; ni < 4; ni++)
        acc[mi][ni] = __builtin_amdgcn_mfma_f32_16x16x32_bf16(af[mi], bfr[ni], acc[mi][ni], 0, 0, 0);
  }

  // epilogue: D row=(lane>>4)*4+r, col=lane&15  [guide §3, m89/m91-verified]
  int col_l = lane & 15, rg = lane >> 4;
#pragma unroll
  for (int mi = 0; mi < 4; mi++) {
#pragma unroll
    for (int ni = 0; ni < 4; ni++) {
      int n = tileN * 128 + wn * 64 + ni * 16 + col_l;
      float bv = (MODE == 0) ? 0.f : bias[n];
#pragma unroll
      for (int r = 0; r < 4; r++) {
        int m = tileM * 128 + wm * 64 + mi * 16 + rg * 4 + r;
        float val = acc[mi][ni][r] + bv;
        if (MODE == 0) {
          int mat = n >> 10, h = (n >> 6) & 15, d = n & 63;
          int b = m >> 10, t = m & 1023;
          size_t off;
          if (mat == 2)  // V^T: [b,h,d,t] (feeds PV MFMA B-operand directly)
            off = ((size_t)(b * H_ + h) * HS_ + d) * T_ + t;
          else           // K,Q: [b,h,t,d]
            off = ((size_t)(b * H_ + h) * T_ + t) * HS_ + d;
          ((u16*)Cout)[(size_t)mat * ((size_t)B_ * H_ * T_ * HS_) + off] = f2b(val);
        } else if (MODE == 1) {
          ((u16*)Cout)[(size_t)m * N + n] = f2b(fmaxf(val, 0.f));
        } else {
          ((float*)Cout)[(size_t)m * N + n] = val;
        }
      }
    }
  }
}

// ---------------------------------------------------------------- attention
// wei[t,s] = k_t . q_s / 8, causal (s<=t), softmax over s; out = wei @ v
// MFMA flash-attention: block = 4 waves = 64 t-rows of one (b,h).
//   S-tile  : mfma(A=K_frag(regs), B=Q rows from LDS)   -> D[t][s]
//   PV-tile : mfma(A=P via LDS relayout, B=V^T from LDS) -> D[t][d]
// Q/V^T staged with global_load_lds, XOR-swizzled (src-side + read-side,
// rule 21): lds byte col c stores global col c ^ ((row&7)<<4).
__global__ __launch_bounds__(256) void attn_kernel(
    const u16* __restrict__ kqv, u16* __restrict__ zb) {
  const u16* Kg  = kqv;
  const u16* Qg  = kqv + (size_t)B_ * H_ * T_ * HS_;
  const u16* Vtg = Qg  + (size_t)B_ * H_ * T_ * HS_;
  int bid = blockIdx.x;
  int ti = 15 - (bid >> 6);        // heavy tiles first
  int bh = bid & 63;               // b*H + h
  size_t ho = (size_t)bh * T_ * HS_;
  const u16* Kh  = Kg  + ho;       // [t][d]
  const u16* Qh  = Qg  + ho;       // [s][d]
  const u16* Vth = Vtg + ho;       // [d][t]  (row stride T_)

  __shared__ __align__(16) u16 Qs[64 * 64];      // 8 KiB, swizzled
  __shared__ __align__(16) u16 Vt[64 * 64];      // 8 KiB, swizzled
  __shared__ __align__(16) u16 Pl[4][16 * 88];   // per-wave P, stride 88 (16B-aligned rows)

  int tid = threadIdx.x;
  int w = tid >> 6, lane = tid & 63;
  int col = lane & 15, g = lane >> 4;

  // K fragments in registers for this wave's 16 t-rows
  bf16x8 kf[2];
  {
    const u16* kr = Kh + (size_t)(ti * 64 + w * 16 + col) * HS_ + g * 8;
    kf[0] = *reinterpret_cast<const bf16x8*>(kr);
    kf[1] = *reinterpret_cast<const bf16x8*>(kr + 32);
  }

  f32x4 o_acc[4];
#pragma unroll
  for (int ni = 0; ni < 4; ni++) o_acc[ni] = (f32x4){0.f, 0.f, 0.f, 0.f};
  float m_run[4], l_run[4];
#pragma unroll
  for (int r = 0; r < 4; r++) { m_run[r] = -1e30f; l_run[r] = 0.f; }

  // staging geometry: each gl_lds16 covers 8 rows (1 KiB); row&7 == lane>>3
  int srow = lane >> 3;                          // 0..7 within chunk
  int scol = ((lane & 7) ^ srow) << 4;           // pre-swizzled source byte col

  for (int jt = 0; jt <= ti; ++jt) {
    __syncthreads();   // prev iter done reading Qs/Vt
    {
      int r0 = w * 16;
      const u16* q0 = Qh + (size_t)(jt * 64 + r0 + srow) * HS_ + (scol >> 1);
      gl_lds16(q0, &Qs[r0 * 64]);
      const u16* q1 = Qh + (size_t)(jt * 64 + r0 + 8 + srow) * HS_ + (scol >> 1);
      gl_lds16(q1, &Qs[(r0 + 8) * 64]);
      const u16* v0 = Vth + (size_t)(r0 + srow) * T_ + jt * 64 + (scol >> 1);
      gl_lds16(v0, &Vt[r0 * 64]);
      const u16* v1 = Vth + (size_t)(r0 + 8 + srow) * T_ + jt * 64 + (scol >> 1);
      gl_lds16(v1, &Vt[(r0 + 8) * 64]);
    }
    __syncthreads();   // staging visible

    // ---- S = K . Q^T  (per wave: 16 t-rows x 64 s-cols)
    f32x4 sc[4];
#pragma unroll
    for (int ni = 0; ni < 4; ni++) sc[ni] = (f32x4){0.f, 0.f, 0.f, 0.f};
#pragma unroll
    for (int kk = 0; kk < 2; kk++) {
#pragma unroll
      for (int ni = 0; ni < 4; ni++) {
        int row = ni * 16 + col;
        int c = (kk * 64 + g * 16) ^ ((row & 7) << 4);
        bf16x8 qf = *reinterpret_cast<const bf16x8*>(&Qs[row * 64 + (c >> 1)]);
        sc[ni] = __builtin_amdgcn_mfma_f32_16x16x32_bf16(kf[kk], qf, sc[ni], 0, 0, 0);
      }
    }

    // ---- online softmax over s (row t lives across the 16-lane group + 4 frags)
    bool last = (jt == ti);
    float p[4][4], alpha[4];
#pragma unroll
    for (int r = 0; r < 4; r++) {
      int t_loc = w * 16 + g * 4 + r;
      float mx = -1e30f;
#pragma unroll
      for (int ni = 0; ni < 4; ni++) {
        float v = sc[ni][r] * 0.125f;
        if (last && (ni * 16 + col) > t_loc) v = -1e30f;   // causal mask
        p[ni][r] = v;
        mx = fmaxf(mx, v);
      }
      mx = fmaxf(mx, __shfl_xor(mx, 1));
      mx = fmaxf(mx, __shfl_xor(mx, 2));
      mx = fmaxf(mx, __shfl_xor(mx, 4));
      mx = fmaxf(mx, __shfl_xor(mx, 8));
      float mnew = fmaxf(m_run[r], mx);
      alpha[r] = __expf(m_run[r] - mnew);
      m_run[r] = mnew;
      float s = 0.f;
#pragma unroll
      for (int ni = 0; ni < 4; ni++) {
        float e = __expf(p[ni][r] - mnew);
        p[ni][r] = e;
        s += e;
      }
      s += __shfl_xor(s, 1);
      s += __shfl_xor(s, 2);
      s += __shfl_xor(s, 4);
      s += __shfl_xor(s, 8);
      l_run[r] = l_run[r] * alpha[r] + s;
    }

    // ---- P -> bf16 via per-wave LDS (D-layout -> A-layout)
#pragma unroll
    for (int r = 0; r < 4; r++) {
      int row = g * 4 + r;
#pragma unroll
      for (int ni = 0; ni < 4; ni++)
        Pl[w][row * 88 + ni * 16 + col] = f2b(p[ni][r]);
    }
#pragma unroll
    for (int ni = 0; ni < 4; ni++)
#pragma unroll
      for (int r = 0; r < 4; r++) o_acc[ni][r] *= alpha[r];

    // ---- O += P . V   (B-operand = V^T rows from swizzled LDS)
#pragma unroll
    for (int kk = 0; kk < 2; kk++) {
      bf16x8 pf = *reinterpret_cast<const bf16x8*>(&Pl[w][col * 88 + kk * 32 + g * 8]);
#pragma unroll
      for (int ni = 0; ni < 4; ni++) {
        int row = ni * 16 + col;
        int c = (kk * 64 + g * 16) ^ ((row & 7) << 4);
        bf16x8 vf = *reinterpret_cast<const bf16x8*>(&Vt[row * 64 + (c >> 1)]);
        o_acc[ni] = __builtin_amdgcn_mfma_f32_16x16x32_bf16(pf, vf, o_acc[ni], 0, 0, 0);
      }
    }
  }

  // ---- epilogue: normalize, write z[b][t][h*64+d] bf16
  int b = bh >> 4, h = bh & 15;
  float inv[4];
#pragma unroll
  for (int r = 0; r < 4; r++) inv[r] = 1.f / l_run[r];
#pragma unroll
  for (int ni = 0; ni < 4; ni++) {
#pragma unroll
    for (int r = 0; r < 4; r++) {
      int t = ti * 64 + w * 16 + g * 4 + r;
      size_t off = ((size_t)(b * T_ + t)) * E_ + h * HS_ + ni * 16 + col;
      zb[off] = f2b(o_acc[ni][r] * inv[r]);
    }
  }
}

// ---------------------------------------------------------------- launch
extern "C" void kernel_launch(void* const* d_in, const int* in_sizes, int n_in,
                              void* d_out, int out_size, void* d_ws, size_t ws_size,
                              hipStream_t stream) {
  const int*   tok    = (const int*)d_in[0];
  const float* tokemb = (const float*)d_in[1];
  const float* posemb = (const float*)d_in[2];
  const float* Wk     = (const float*)d_in[3];
  const float* Wq     = (const float*)d_in[4];
  const float* Wv     = (const float*)d_in[5];
  const float* ffW    = (const float*)d_in[6];
  const float* ffb    = (const float*)d_in[7];
  const float* outW   = (const float*)d_in[8];
  const float* outb   = (const float*)d_in[9];

  char* ws = (char*)d_ws;
  const size_t MiB = 1024 * 1024;
  u16*   xb    = (u16*)(ws + 0);          // 8 MiB   [dead after QKV gemm]
  u16*   Wt    = (u16*)(ws + 8 * MiB);    // 6 MiB   (3072 x 1024 bf16)
  u16*   kqv   = (u16*)(ws + 14 * MiB);   // 24 MiB bf16 (K,Q [bhtd]; V^T [bhdt]) [dead after attn]
  u16*   zbuf  = (u16*)(ws + 62 * MiB);   // 8 MiB   [dead after ff gemm]
  u16*   ffWt  = (u16*)(ws + 70 * MiB);   // 2 MiB
  u16*   z2b   = (u16*)(ws + 72 * MiB);   // 8 MiB
  u16*   outWt = (u16*)(ws + 0);          // 62.5 MiB, aliases [0,62.5) - written
                                          // AFTER ff gemm, so aliasing is safe
  float* outp  = (float*)d_out;

  // 1. embed -> x bf16
  embed_kernel<<<B_ * T_, 256, 0, stream>>>(tok, tokemb, posemb, xb);
  // 2. W{k,q,v}: (H,E,HS) -> per-head (HS,E) bf16, concatenated to (3072,1024)
  transpose_cast_kernel<<<dim3(16, 1, 16), 256, 0, stream>>>(Wk, Wt,               1024, 64);
  transpose_cast_kernel<<<dim3(16, 1, 16), 256, 0, stream>>>(Wq, Wt + 1024 * 1024, 1024, 64);
  transpose_cast_kernel<<<dim3(16, 1, 16), 256, 0, stream>>>(Wv, Wt + 2048 * 1024, 1024, 64);
  // 3. fused QKV gemm: (4096x1024)@(1024x3072) -> scatter bf16 k,q (b,h,t,d), v^T (b,h,d,t)
  gemm_bt_kernel<0><<<32 * 24, 256, 0, stream>>>(xb, Wt, nullptr, kqv, 4096, 3072, 1024, 24);
  // 4. attention (MFMA flash) -> z bf16 (B,T,E)
  attn_kernel<<<B_ * H_ * 16, 256, 0, stream>>>(kqv, zbuf);
  // 5. ff: relu(z @ ff_W + ff_b) -> bf16
  transpose_cast_kernel<<<dim3(16, 16, 1), 256, 0, stream>>>(ffW, ffWt, 1024, 1024);
  gemm_bt_kernel<1><<<32 * 8, 256, 0, stream>>>(zbuf, ffWt, ffb, z2b, 4096, 1024, 1024, 8);
  // 6. out_W: (1024,32000) -> (32000,1024) bf16 (after ff gemm: aliases dead bufs)
  transpose_cast_kernel<<<dim3(16, 500, 1), 256, 0, stream>>>(outW, outWt, 1024, 32000);
  // 7. logits = z2 @ out_W + out_b -> d_out fp32
  gemm_bt_kernel<2><<<32 * 250, 256, 0, stream>>>(z2b, outWt, outb, outp, 4096, 32000, 1024, 250);
}